// Round 9
// baseline (933.679 us; speedup 1.0000x reference)
//
#include <hip/hip_runtime.h>
#include <math.h>

// Radial NUFFT + Pipe-Menon density compensation, MI355X (gfx950).
// bf16 MFMA (16x16x32), 2-term hi/lo split (3 products). Round 9: adjoint
// K-loop made barrier-free and LDS-free (wave-private E-build from packed AS,
// direct coalesced BS fragment loads, register double-buffer prefetch) and
// global-atomic count cut 4x (SPLITS 256->64): r8's WRITE_SIZE showed every
// atomic line spilling to HBM (18.9M atomics = 73.7 MB HBM writes).

#define MTOT 36864      // N_SHOTS*N_SAMPLES == NPIX*NPIX
#define NPIX 192
#define SPLITS 64
#define MPS (MTOT / SPLITS)     // 576 m per split
#define ADJ_CHUNKS (MPS / 16)   // 36 chunks of 16 m (32 K) per split
#define PG 4                    // partial output images

typedef __attribute__((ext_vector_type(8))) short s16x8;
typedef __attribute__((ext_vector_type(4))) float f32x4;
typedef __attribute__((ext_vector_type(4))) unsigned u32x4;

__device__ __forceinline__ f32x4 mfma_bf16(u32x4 a, u32x4 b, f32x4 c) {
    return __builtin_amdgcn_mfma_f32_16x16x32_bf16(
        __builtin_bit_cast(s16x8, a), __builtin_bit_cast(s16x8, b), c, 0, 0, 0);
}

// Split (a,b) into packed bf16 pairs: hi = (bf16(a) | bf16(b)<<16), lo = residuals.
__device__ __forceinline__ void split_pk(float a, float b, unsigned &hi, unsigned &lo) {
    const unsigned ua = __float_as_uint(a), ub = __float_as_uint(b);
    const unsigned ha = (ua + 0x8000u) & 0xffff0000u;
    const unsigned hb = (ub + 0x8000u) & 0xffff0000u;
    hi = (ha >> 16) | hb;
    const float la = a - __uint_as_float(ha);
    const float lb = b - __uint_as_float(hb);
    lo = ((__float_as_uint(la) + 0x8000u) >> 16) |
         ((__float_as_uint(lb) + 0x8000u) & 0xffff0000u);
}

// k split into 12-bit hi + residual so kh*p (p integer, |p|<=96) is EXACT in fp32.
__device__ __forceinline__ void ksplit(float k, float &kh, float &kl) {
    kh = __uint_as_float(__float_as_uint(k) & 0xfffff000u);
    kl = k - kh;
}
__device__ __forceinline__ float redphase(float kh, float kl, float p) {
    float r = kh * p;
    r -= rintf(r);
    r = fmaf(kl, p, r);
    return r;                   // revolutions, |r| <= ~0.512
}
__device__ __forceinline__ unsigned rot16(unsigned v) {
    return __builtin_amdgcn_alignbit(v, v, 16);
}

// ---------------------------------------------------------------------------
// Precompute packed phasor (cos, -sin) hi/lo, CHUNK-CONTIGUOUS layout:
// PS[mc][plane][coord][mi], mc = m>>4, mi = m&15; chunk region = 6144 u32.
// comp=0: kx with coord=x (A matrix); comp=1: ky with coord=y (B matrix).
__global__ void precompP_k(const float* __restrict__ traj, const int comp,
                           unsigned* __restrict__ PS) {
    const int m = blockIdx.x * 256 + threadIdx.x;
    const int c = blockIdx.y;
    float kh, kl; ksplit(traj[2 * m + comp], kh, kl);
    const float ph = redphase(kh, kl, (float)(c - 96));
    const float co = __builtin_amdgcn_cosf(ph);
    const float si = __builtin_amdgcn_sinf(ph);
    unsigned h, l; split_pk(co, -si, h, l);
    const int mc = m >> 4, mi = m & 15;
    PS[(size_t)mc * 6144 + c * 16 + mi]        = h;
    PS[(size_t)mc * 6144 + 3072 + c * 16 + mi] = l;
}

__global__ void winit_k(float* __restrict__ wr, float* __restrict__ wi) {
    const int m = blockIdx.x * 256 + threadIdx.x;
    wr[m] = 1.f; wi[m] = 0.f;
}

// ---------------------------------------------------------------------------
// Adjoint: out[x,y] += sum_m E[m,x]*conj(B[m,y]),  E = conj(A[m,x])*d[m].
// Block: 4 waves (2x2 of 48x48) = 96x x 96y quarter; grid (4, 64 splits) =
// 256 blocks (1/CU). K-loop: NO barriers, NO LDS — each wave builds its own
// E fragments (r8 formulas) from packed AS + d, B fragments loaded directly
// from packed BS; next chunk's A/B/d register-prefetched.
__global__ __launch_bounds__(256) void adj_mfma_k(
    const float* __restrict__ dre, const float* __restrict__ dim_,
    const unsigned* __restrict__ AS, const unsigned* __restrict__ BS,
    float* __restrict__ outP)
{
    const int tid = threadIdx.x;
    const int lane = tid & 63, wid = tid >> 6;     // wid 0..3
    const int l15 = lane & 15, qd = lane >> 4;
    const int bx = blockIdx.x & 1, by = blockIdx.x >> 1;
    const int wi = wid & 1, wj = wid >> 1;
    const int s = blockIdx.y;                      // split 0..63
    float* outRe = outP + (size_t)(s & (PG - 1)) * (2 * MTOT);
    float* outIm = outRe + MTOT;

    f32x4 accRe[3][3], accIm[3][3];
    #pragma unroll
    for (int i = 0; i < 3; ++i)
        #pragma unroll
        for (int j = 0; j < 3; ++j) {
            accRe[i][j] = (f32x4){0.f, 0.f, 0.f, 0.f};
            accIm[i][j] = (f32x4){0.f, 0.f, 0.f, 0.f};
        }

    // per-wave fragment offsets (within a 6144-word chunk region)
    int aoff[3], boff[3];
    #pragma unroll
    for (int t = 0; t < 3; ++t) {
        aoff[t] = (bx * 96 + wi * 48 + t * 16 + l15) * 16 + qd * 4;
        boff[t] = (by * 96 + wj * 48 + t * 16 + l15) * 16 + qd * 4;
    }
    const int mrow = s * MPS;

    u32x4 Ah[2][3], Al[2][3], Bh[2][3], Bl[2][3];
    float dbr[2][4], dbi[2][4];

    {   // load chunk 0 into buffer 0
        const unsigned* R = AS + (size_t)(s * ADJ_CHUNKS) * 6144;
        const unsigned* Bc = BS + (size_t)(s * ADJ_CHUNKS) * 6144;
        #pragma unroll
        for (int t = 0; t < 3; ++t) {
            Ah[0][t] = *(const u32x4*)(R + aoff[t]);
            Al[0][t] = *(const u32x4*)(R + 3072 + aoff[t]);
            Bh[0][t] = *(const u32x4*)(Bc + boff[t]);
            Bl[0][t] = *(const u32x4*)(Bc + 3072 + boff[t]);
        }
        #pragma unroll
        for (int r = 0; r < 4; ++r) {
            dbr[0][r] = dre[mrow + qd * 4 + r];
            dbi[0][r] = dim_[mrow + qd * 4 + r];
        }
    }

    for (int ch = 0; ch < ADJ_CHUNKS; ++ch) {
        const int cur = ch & 1, nxt = cur ^ 1;
        if (ch + 1 < ADJ_CHUNKS) {                 // prefetch chunk ch+1
            const unsigned* R = AS + (size_t)(s * ADJ_CHUNKS + ch + 1) * 6144;
            const unsigned* Bc = BS + (size_t)(s * ADJ_CHUNKS + ch + 1) * 6144;
            #pragma unroll
            for (int t = 0; t < 3; ++t) {
                Ah[nxt][t] = *(const u32x4*)(R + aoff[t]);
                Al[nxt][t] = *(const u32x4*)(R + 3072 + aoff[t]);
                Bh[nxt][t] = *(const u32x4*)(Bc + boff[t]);
                Bl[nxt][t] = *(const u32x4*)(Bc + 3072 + boff[t]);
            }
            const int mbn = mrow + (ch + 1) * 16 + qd * 4;
            #pragma unroll
            for (int r = 0; r < 4; ++r) {
                dbr[nxt][r] = dre[mbn + r];
                dbi[nxt][r] = dim_[mbn + r];
            }
        }

        // wave-private E-build (r8-verified formulas)
        u32x4 Eh[3], El[3];
        #pragma unroll
        for (int si = 0; si < 3; ++si)
            #pragma unroll
            for (int r = 0; r < 4; ++r) {
                const unsigned hA = Ah[cur][si][r], lA = Al[cur][si][r];
                const float ca  = __uint_as_float(hA << 16) + __uint_as_float(lA << 16);
                const float msa = __uint_as_float(hA & 0xffff0000u) +
                                  __uint_as_float(lA & 0xffff0000u);   // = -sin
                const float dr_ = dbr[cur][r], di_ = dbi[cur][r];
                const float Er = ca * dr_ + msa * di_;
                const float Ei = ca * di_ - msa * dr_;
                unsigned eh, el; split_pk(Er, Ei, eh, el);
                Eh[si][r] = eh; El[si][r] = el;
            }

        #pragma unroll
        for (int sj = 0; sj < 3; ++sj) {
            const u32x4 Ph = Bh[cur][sj], Pl = Bl[cur][sj];   // (cos, -sin)
            u32x4 Qh, Ql;
            #pragma unroll
            for (int r = 0; r < 4; ++r) {
                Qh[r] = rot16(Ph[r]) ^ 0x00008000u;           // (sin, cos)
                Ql[r] = rot16(Pl[r]) ^ 0x00008000u;
            }
            #pragma unroll
            for (int si = 0; si < 3; ++si) {
                accRe[si][sj] = mfma_bf16(Eh[si], Ph, accRe[si][sj]);
                accRe[si][sj] = mfma_bf16(Eh[si], Pl, accRe[si][sj]);
                accRe[si][sj] = mfma_bf16(El[si], Ph, accRe[si][sj]);
                accIm[si][sj] = mfma_bf16(Eh[si], Qh, accIm[si][sj]);
                accIm[si][sj] = mfma_bf16(Eh[si], Ql, accIm[si][sj]);
                accIm[si][sj] = mfma_bf16(El[si], Qh, accIm[si][sj]);
            }
        }
    }

    // epilogue: direct global atomics into partial image (r8-verified mapping)
    #pragma unroll
    for (int si = 0; si < 3; ++si)
        #pragma unroll
        for (int sj = 0; sj < 3; ++sj)
            #pragma unroll
            for (int rg = 0; rg < 4; ++rg) {
                const int x = bx * 96 + wi * 48 + si * 16 + qd * 4 + rg;  // C/D row
                const int y = by * 96 + wj * 48 + sj * 16 + l15;          // C/D col
                atomicAdd(outRe + x * NPIX + y, accRe[si][sj][rg]);
                atomicAdd(outIm + x * NPIX + y, accIm[si][sj][rg]);
            }
}

// ---------------------------------------------------------------------------
// fwdq: q[m] = sum_x A[m,x] * (sum_y B[m,y]*g[x,y]).   (unchanged from r5)
__device__ __forceinline__ void fw_stage_load(const unsigned* __restrict__ Ghi,
                                              const unsigned* __restrict__ Glo,
                                              int tid, int koff, u32x4 st[3]) {
    #pragma unroll
    for (int j = 0; j < 3; ++j) {
        const int li = tid + j * 576;
        if (li < 1536) {
            const int row = li >> 3, pl = (li >> 2) & 1, qt = li & 3;
            const unsigned* src = pl ? Glo : Ghi;
            st[j] = *(const u32x4*)(src + row * 192 + koff + qt * 4);
        }
    }
}
__device__ __forceinline__ void fw_stage_write(unsigned* sb, int tid, const u32x4 st[3]) {
    #pragma unroll
    for (int j = 0; j < 3; ++j) {
        const int li = tid + j * 576;
        if (li < 1536) {
            const int row = li >> 3, pl = (li >> 2) & 1, qt = li & 3;
            *(u32x4*)(sb + pl * 3840 + row * 20 + qt * 4) = st[j];
        }
    }
}

__global__ __launch_bounds__(576) void fwdq_k(
    const float* __restrict__ traj,
    const unsigned* __restrict__ Ghi, const unsigned* __restrict__ Glo,
    float* __restrict__ wre, float* __restrict__ wim,
    const int mode,
    float* __restrict__ qre, float* __restrict__ qim)
{
    __shared__ unsigned sG[2][2 * 3840];   // 60 KB
    const int tid = threadIdx.x;
    const int lane = tid & 63, wid = tid >> 6;         // wid 0..8
    const int l15 = lane & 15, q = lane >> 4;
    const int m = (blockIdx.x * 9 + wid) * 16 + l15;
    const float2 kk = *(const float2*)(traj + 2 * m);
    float kxh, kxl, kyh, kyl;
    ksplit(kk.x, kxh, kxl);
    ksplit(kk.y, kyh, kyl);

    f32x4 tre[12], tim[12];
    #pragma unroll
    for (int i = 0; i < 12; ++i) {
        tre[i] = (f32x4){0.f, 0.f, 0.f, 0.f};
        tim[i] = (f32x4){0.f, 0.f, 0.f, 0.f};
    }

    float bc, bs;
    { const float ph = redphase(kyh, kyl, (float)(q * 4 - 96)); 
      bc = __builtin_amdgcn_cosf(ph); bs = __builtin_amdgcn_sinf(ph); }
    const float r1c = __builtin_amdgcn_cosf(kk.y), r1s = __builtin_amdgcn_sinf(kk.y);
    float r16c, r16s;
    { float g = kk.y * 16.f; g -= rintf(g);
      r16c = __builtin_amdgcn_cosf(g); r16s = __builtin_amdgcn_sinf(g); }

    u32x4 st[3];
    fw_stage_load(Ghi, Glo, tid, 0, st);
    fw_stage_write(&sG[0][0], tid, st);
    __syncthreads();

    for (int ch = 0; ch < 12; ++ch) {
        if (ch < 11) fw_stage_load(Ghi, Glo, tid, (ch + 1) * 16, st);

        u32x4 Ph, Pl, Qh, Ql;
        {
            float c = bc, s = bs;
            #pragma unroll
            for (int r = 0; r < 4; ++r) {
                unsigned h, l; split_pk(c, s, h, l);
                Ph[r] = h; Pl[r] = l;
                Qh[r] = rot16(h) ^ 0x00008000u;
                Ql[r] = rot16(l) ^ 0x00008000u;
                const float nc = c * r1c - s * r1s, ns = s * r1c + c * r1s;
                c = nc; s = ns;
            }
            const float nbc = bc * r16c - bs * r16s, nbs = bs * r16c + bc * r16s;
            bc = nbc; bs = nbs;
        }

        const unsigned* sb = &sG[ch & 1][0];
        #pragma unroll
        for (int si = 0; si < 12; ++si) {
            const int base = (si * 16 + l15) * 20 + q * 4;
            const u32x4 gh = *(const u32x4*)(sb + base);
            const u32x4 gl = *(const u32x4*)(sb + 3840 + base);
            tre[si] = mfma_bf16(gh, Ph, tre[si]);
            tre[si] = mfma_bf16(gh, Pl, tre[si]);
            tre[si] = mfma_bf16(gl, Ph, tre[si]);
            tim[si] = mfma_bf16(gh, Qh, tim[si]);
            tim[si] = mfma_bf16(gh, Ql, tim[si]);
            tim[si] = mfma_bf16(gl, Qh, tim[si]);
        }

        if (ch < 11) {
            __syncthreads();
            fw_stage_write(&sG[(ch + 1) & 1][0], tid, st);
            __syncthreads();
        }
    }

    float qr = 0.f, qi = 0.f;
    {
        float g = kk.x * 16.f; g -= rintf(g);
        const float rc = __builtin_amdgcn_cosf(g), rs = __builtin_amdgcn_sinf(g);
        #pragma unroll
        for (int rg = 0; rg < 4; ++rg) {
            const float ph = redphase(kxh, kxl, (float)(q * 4 + rg - 96));
            float c = __builtin_amdgcn_cosf(ph), s = __builtin_amdgcn_sinf(ph);
            #pragma unroll
            for (int si = 0; si < 12; ++si) {
                const float tr = tre[si][rg], ti = tim[si][rg];
                qr += c * tr + s * ti;
                qi += c * ti - s * tr;
                const float nc = c * rc - s * rs, ns = s * rc + c * rs;
                c = nc; s = ns;
            }
        }
    }
    qr += __shfl_xor(qr, 16); qi += __shfl_xor(qi, 16);
    qr += __shfl_xor(qr, 32); qi += __shfl_xor(qi, 32);
    if (lane < 16) {
        if (mode == 0) {
            const float den = fmaxf(sqrtf(qr * qr + qi * qi), 1e-20f);
            wre[m] /= den; wim[m] /= den;
        } else {
            const float sc = sqrtf(wre[m] * wre[m] + wim[m] * wim[m]);
            qre[m] = qr * sc; qim[m] = qi * sc;
        }
    }
}

// ---------------------------------------------------------------------------
__global__ void presplit_k(const float* __restrict__ re, const float* __restrict__ im,
                           unsigned* __restrict__ Gh, unsigned* __restrict__ Gl) {
    const int e = blockIdx.x * 256 + threadIdx.x;
    unsigned h, l;
    split_pk(re[e], im[e], h, l);     // low16 = re (even K), high16 = im (odd K)
    Gh[e] = h; Gl[e] = l;
}

// Reduce PG partial images + presplit (pipe path)
__global__ void presplitP_k(const float* __restrict__ outP,
                            unsigned* __restrict__ Gh, unsigned* __restrict__ Gl) {
    const int e = blockIdx.x * 256 + threadIdx.x;
    float re = 0.f, im = 0.f;
    #pragma unroll
    for (int g = 0; g < PG; ++g) {
        re += outP[(size_t)g * (2 * MTOT) + e];
        im += outP[(size_t)g * (2 * MTOT) + MTOT + e];
    }
    unsigned h, l;
    split_pk(re, im, h, l);
    Gh[e] = h; Gl[e] = l;
}

// Reduce PG partial images -> final output
__global__ void reduceOut_k(const float* __restrict__ outP, float* __restrict__ out) {
    const int e = blockIdx.x * 256 + threadIdx.x;
    float re = 0.f, im = 0.f;
    #pragma unroll
    for (int g = 0; g < PG; ++g) {
        re += outP[(size_t)g * (2 * MTOT) + e];
        im += outP[(size_t)g * (2 * MTOT) + MTOT + e];
    }
    out[e] = re; out[MTOT + e] = im;
}

// ---------------------------------------------------------------------------
extern "C" void kernel_launch(void* const* d_in, const int* in_sizes, int n_in,
                              void* d_out, int out_size, void* d_ws, size_t ws_size,
                              hipStream_t stream)
{
    const float* xin  = (const float*)d_in[0];   // (2,192,192)
    const float* traj = (const float*)d_in[1];   // (36864,2)
    float* out = (float*)d_out;                  // (2,192,192)

    char* pb = (char*)d_ws;
    unsigned* AS = (unsigned*)pb; pb += (size_t)2304 * 6144 * 4;   // 56.6 MB
    unsigned* BS = (unsigned*)pb; pb += (size_t)2304 * 6144 * 4;   // 56.6 MB
    float* outP = (float*)pb; pb += (size_t)PG * 2 * MTOT * 4;
    float* wr   = (float*)pb; pb += MTOT * 4;
    float* wi   = (float*)pb; pb += MTOT * 4;
    float* dre  = (float*)pb; pb += MTOT * 4;
    float* dim_ = (float*)pb; pb += MTOT * 4;
    unsigned* Ghi = (unsigned*)pb; pb += MTOT * 4;
    unsigned* Glo = (unsigned*)pb; pb += MTOT * 4;

    precompP_k<<<dim3(MTOT / 256, NPIX), 256, 0, stream>>>(traj, 0, AS);
    precompP_k<<<dim3(MTOT / 256, NPIX), 256, 0, stream>>>(traj, 1, BS);
    winit_k<<<MTOT / 256, 256, 0, stream>>>(wr, wi);

    for (int it = 0; it < 3; ++it) {
        hipMemsetAsync(outP, 0, (size_t)PG * 2 * MTOT * 4, stream);
        adj_mfma_k<<<dim3(4, SPLITS), 256, 0, stream>>>(wr, wi, AS, BS, outP);
        presplitP_k<<<MTOT / 256, 256, 0, stream>>>(outP, Ghi, Glo);
        fwdq_k<<<256, 576, 0, stream>>>(traj, Ghi, Glo, wr, wi, 0, dre, dim_);
    }

    presplit_k<<<MTOT / 256, 256, 0, stream>>>(xin, xin + MTOT, Ghi, Glo);
    fwdq_k<<<256, 576, 0, stream>>>(traj, Ghi, Glo, wr, wi, 1, dre, dim_);
    hipMemsetAsync(outP, 0, (size_t)PG * 2 * MTOT * 4, stream);
    adj_mfma_k<<<dim3(4, SPLITS), 256, 0, stream>>>(dre, dim_, AS, BS, outP);
    reduceOut_k<<<MTOT / 256, 256, 0, stream>>>(outP, out);
}

// Round 10
// 591.242 us; speedup vs baseline: 1.5792x; 1.5792x over previous
//
#include <hip/hip_runtime.h>
#include <math.h>

// Radial NUFFT + Pipe-Menon density compensation, MI355X (gfx950).
// bf16 MFMA (16x16x32), 2-term hi/lo split (3 products). Round 10: adjoint
// K-loop rebuilt on the m97 pattern: async global_load_lds (16B) stages each
// chunk into double-buffered LDS with ONE barrier per chunk (prefetch issued
// at loop top, drained after the full compute phase), XOR bank-swizzle for
// conflict-free b128 frag reads, lean registers (no VGPR staging buffers).
// E-build math, MFMA sequence, epilogue, fwdq: r8-verbatim.

#define MTOT 36864      // N_SHOTS*N_SAMPLES == NPIX*NPIX
#define NPIX 192
#define SPLITS 256
#define MPS (MTOT / SPLITS)     // 144 m per split
#define ADJ_CHUNKS (MPS / 16)   // 9 chunks of 16 m (32 K) per split
#define PG 4                    // partial output images

typedef __attribute__((ext_vector_type(8))) short s16x8;
typedef __attribute__((ext_vector_type(4))) float f32x4;
typedef __attribute__((ext_vector_type(4))) unsigned u32x4;

__device__ __forceinline__ f32x4 mfma_bf16(u32x4 a, u32x4 b, f32x4 c) {
    return __builtin_amdgcn_mfma_f32_16x16x32_bf16(
        __builtin_bit_cast(s16x8, a), __builtin_bit_cast(s16x8, b), c, 0, 0, 0);
}

// async 16B/lane global->LDS (DMA, no VGPR roundtrip); LDS dest semantics:
// wave-uniform base + lane*16 (our layout matches exactly).
__device__ __forceinline__ void g2l16(const void* g, void* l) {
    __builtin_amdgcn_global_load_lds(
        (const __attribute__((address_space(1))) void*)g,
        (__attribute__((address_space(3))) void*)l, 16, 0, 0);
}

// Split (a,b) into packed bf16 pairs: hi = (bf16(a) | bf16(b)<<16), lo = residuals.
__device__ __forceinline__ void split_pk(float a, float b, unsigned &hi, unsigned &lo) {
    const unsigned ua = __float_as_uint(a), ub = __float_as_uint(b);
    const unsigned ha = (ua + 0x8000u) & 0xffff0000u;
    const unsigned hb = (ub + 0x8000u) & 0xffff0000u;
    hi = (ha >> 16) | hb;
    const float la = a - __uint_as_float(ha);
    const float lb = b - __uint_as_float(hb);
    lo = ((__float_as_uint(la) + 0x8000u) >> 16) |
         ((__float_as_uint(lb) + 0x8000u) & 0xffff0000u);
}

// k split into 12-bit hi + residual so kh*p (p integer, |p|<=96) is EXACT in fp32.
__device__ __forceinline__ void ksplit(float k, float &kh, float &kl) {
    kh = __uint_as_float(__float_as_uint(k) & 0xfffff000u);
    kl = k - kh;
}
__device__ __forceinline__ float redphase(float kh, float kl, float p) {
    float r = kh * p;
    r -= rintf(r);
    r = fmaf(kl, p, r);
    return r;                   // revolutions, |r| <= ~0.512
}
__device__ __forceinline__ unsigned rot16(unsigned v) {
    return __builtin_amdgcn_alignbit(v, v, 16);
}

// ---------------------------------------------------------------------------
// Precompute packed phasor (cos, -sin) hi/lo, CHUNK-CONTIGUOUS layout with
// bank swizzle: region [mc][plane][c(192)][mi(16)], word index
// mc*6144 + plane*3072 + c*16 + (mi ^ swz(c)), swz(c) = ((c^(c>>2))&3)<<2.
// comp=0: kx (A matrix, coord=x); comp=1: ky (B matrix, coord=y).
__global__ void precompP_k(const float* __restrict__ traj, const int comp,
                           unsigned* __restrict__ PS) {
    const int m = blockIdx.x * 256 + threadIdx.x;
    const int c = blockIdx.y;
    float kh, kl; ksplit(traj[2 * m + comp], kh, kl);
    const float ph = redphase(kh, kl, (float)(c - 96));
    const float co = __builtin_amdgcn_cosf(ph);
    const float si = __builtin_amdgcn_sinf(ph);
    unsigned h, l; split_pk(co, -si, h, l);
    const int mc = m >> 4, mi = (m & 15) ^ (((c ^ (c >> 2)) & 3) << 2);
    PS[(size_t)mc * 6144 + c * 16 + mi]        = h;
    PS[(size_t)mc * 6144 + 3072 + c * 16 + mi] = l;
}

__global__ void winit_k(float* __restrict__ wr, float* __restrict__ wi) {
    const int m = blockIdx.x * 256 + threadIdx.x;
    wr[m] = 1.f; wi[m] = 0.f;
}

// ---------------------------------------------------------------------------
// Adjoint: out[x,y] += sum_m E[m,x]*conj(B[m,y]),  E = conj(A[m,x])*d[m].
// Block: 4 waves (2x2 of 48x48) = 96x x 96y quarter; grid (4, 256 splits).
// Chunk staged via 6x global_load_lds into dbuf LDS (24 KB/chunk), single
// barrier per chunk; frag b128 reads bank-swizzled (2-way, free).
__global__ __launch_bounds__(256) void adj_mfma_k(
    const float* __restrict__ dre, const float* __restrict__ dim_,
    const unsigned* __restrict__ AS, const unsigned* __restrict__ BS,
    float* __restrict__ outP)
{
    __shared__ unsigned sAB[2][6144];              // 48 KB double buffer
    const int tid = threadIdx.x;
    const int lane = tid & 63, wid = tid >> 6;     // wid 0..3
    const int l15 = lane & 15, qd = lane >> 4;
    const int bx = blockIdx.x & 1, by = blockIdx.x >> 1;
    const int wi = wid & 1, wj = wid >> 1;
    const int s = blockIdx.y;                      // split 0..255
    float* outRe = outP + (size_t)(s & (PG - 1)) * (2 * MTOT);
    float* outIm = outRe + MTOT;

    f32x4 accRe[3][3], accIm[3][3];
    #pragma unroll
    for (int i = 0; i < 3; ++i)
        #pragma unroll
        for (int j = 0; j < 3; ++j) {
            accRe[i][j] = (f32x4){0.f, 0.f, 0.f, 0.f};
            accIm[i][j] = (f32x4){0.f, 0.f, 0.f, 0.f};
        }

    // staging source pointers for chunk 0 (advanced 6144 words per chunk).
    // LDS flat layout per buf: [A pl0 |A pl1 |B pl0 |B pl1], 1536 words each.
    const unsigned* gp[6];
    {
        const unsigned* A0 = AS + (size_t)(s * ADJ_CHUNKS) * 6144;
        const unsigned* B0 = BS + (size_t)(s * ADJ_CHUNKS) * 6144;
        #pragma unroll
        for (int j = 0; j < 6; ++j) {
            const int F = j * 1024 + tid * 4;
            if (F < 1536)      gp[j] = A0 + bx * 1536 + F;
            else if (F < 3072) gp[j] = A0 + 3072 + bx * 1536 + (F - 1536);
            else if (F < 4608) gp[j] = B0 + by * 1536 + (F - 3072);
            else               gp[j] = B0 + 3072 + by * 1536 + (F - 4608);
        }
    }
    // fragment LDS word offsets (plane-0; plane-1 = +1536)
    int aA[3], aB[3];
    #pragma unroll
    for (int t = 0; t < 3; ++t) {
        const int cA = wi * 48 + t * 16 + l15;
        aA[t] = cA * 16 + ((qd ^ ((cA ^ (cA >> 2)) & 3)) << 2);
        const int cB = wj * 48 + t * 16 + l15;
        aB[t] = 3072 + cB * 16 + ((qd ^ ((cB ^ (cB >> 2)) & 3)) << 2);
    }
    const int mrow = s * MPS;

    float dbr[2][4], dbi[2][4];
    #pragma unroll
    for (int r = 0; r < 4; ++r) {
        dbr[0][r] = dre[mrow + qd * 4 + r];
        dbi[0][r] = dim_[mrow + qd * 4 + r];
    }
    #pragma unroll
    for (int j = 0; j < 6; ++j)
        g2l16(gp[j], &sAB[0][j * 1024 + tid * 4]);
    __syncthreads();

    for (int ch = 0; ch < ADJ_CHUNKS; ++ch) {
        const int cur = ch & 1, nxt = cur ^ 1;
        if (ch + 1 < ADJ_CHUNKS) {                 // async prefetch chunk ch+1
            #pragma unroll
            for (int j = 0; j < 6; ++j) {
                gp[j] += 6144;
                g2l16(gp[j], &sAB[nxt][j * 1024 + tid * 4]);
            }
            const int mbn = mrow + (ch + 1) * 16 + qd * 4;
            #pragma unroll
            for (int r = 0; r < 4; ++r) {
                dbr[nxt][r] = dre[mbn + r];
                dbi[nxt][r] = dim_[mbn + r];
            }
        }

        // E fragments from staged A (r8-verified math)
        u32x4 Eh[3], El[3];
        #pragma unroll
        for (int si = 0; si < 3; ++si) {
            const u32x4 Ah = *(const u32x4*)(&sAB[cur][aA[si]]);
            const u32x4 Al = *(const u32x4*)(&sAB[cur][1536 + aA[si]]);
            #pragma unroll
            for (int r = 0; r < 4; ++r) {
                const unsigned hA = Ah[r], lA = Al[r];
                const float ca  = __uint_as_float(hA << 16) + __uint_as_float(lA << 16);
                const float msa = __uint_as_float(hA & 0xffff0000u) +
                                  __uint_as_float(lA & 0xffff0000u);   // = -sin
                const float dr_ = dbr[cur][r], di_ = dbi[cur][r];
                const float Er = ca * dr_ + msa * di_;
                const float Ei = ca * di_ - msa * dr_;
                unsigned eh, el; split_pk(Er, Ei, eh, el);
                Eh[si][r] = eh; El[si][r] = el;
            }
        }

        #pragma unroll
        for (int sj = 0; sj < 3; ++sj) {
            const u32x4 Ph = *(const u32x4*)(&sAB[cur][aB[sj]]);          // (cb,-sb)
            const u32x4 Pl = *(const u32x4*)(&sAB[cur][1536 + aB[sj]]);
            u32x4 Qh, Ql;
            #pragma unroll
            for (int r = 0; r < 4; ++r) {
                Qh[r] = rot16(Ph[r]) ^ 0x00008000u;                      // (sb, cb)
                Ql[r] = rot16(Pl[r]) ^ 0x00008000u;
            }
            #pragma unroll
            for (int si = 0; si < 3; ++si) {
                accRe[si][sj] = mfma_bf16(Eh[si], Ph, accRe[si][sj]);
                accRe[si][sj] = mfma_bf16(Eh[si], Pl, accRe[si][sj]);
                accRe[si][sj] = mfma_bf16(El[si], Ph, accRe[si][sj]);
                accIm[si][sj] = mfma_bf16(Eh[si], Qh, accIm[si][sj]);
                accIm[si][sj] = mfma_bf16(Eh[si], Ql, accIm[si][sj]);
                accIm[si][sj] = mfma_bf16(El[si], Qh, accIm[si][sj]);
            }
        }
        __syncthreads();   // drains staging (issued ~full compute phase ago)
    }

    // epilogue: direct global atomics into partial image (r8-verified mapping)
    #pragma unroll
    for (int si = 0; si < 3; ++si)
        #pragma unroll
        for (int sj = 0; sj < 3; ++sj)
            #pragma unroll
            for (int rg = 0; rg < 4; ++rg) {
                const int x = bx * 96 + wi * 48 + si * 16 + qd * 4 + rg;  // C/D row
                const int y = by * 96 + wj * 48 + sj * 16 + l15;          // C/D col
                atomicAdd(outRe + x * NPIX + y, accRe[si][sj][rg]);
                atomicAdd(outIm + x * NPIX + y, accIm[si][sj][rg]);
            }
}

// ---------------------------------------------------------------------------
// fwdq: q[m] = sum_x A[m,x] * (sum_y B[m,y]*g[x,y]).   (unchanged from r5)
__device__ __forceinline__ void fw_stage_load(const unsigned* __restrict__ Ghi,
                                              const unsigned* __restrict__ Glo,
                                              int tid, int koff, u32x4 st[3]) {
    #pragma unroll
    for (int j = 0; j < 3; ++j) {
        const int li = tid + j * 576;
        if (li < 1536) {
            const int row = li >> 3, pl = (li >> 2) & 1, qt = li & 3;
            const unsigned* src = pl ? Glo : Ghi;
            st[j] = *(const u32x4*)(src + row * 192 + koff + qt * 4);
        }
    }
}
__device__ __forceinline__ void fw_stage_write(unsigned* sb, int tid, const u32x4 st[3]) {
    #pragma unroll
    for (int j = 0; j < 3; ++j) {
        const int li = tid + j * 576;
        if (li < 1536) {
            const int row = li >> 3, pl = (li >> 2) & 1, qt = li & 3;
            *(u32x4*)(sb + pl * 3840 + row * 20 + qt * 4) = st[j];
        }
    }
}

__global__ __launch_bounds__(576) void fwdq_k(
    const float* __restrict__ traj,
    const unsigned* __restrict__ Ghi, const unsigned* __restrict__ Glo,
    float* __restrict__ wre, float* __restrict__ wim,
    const int mode,
    float* __restrict__ qre, float* __restrict__ qim)
{
    __shared__ unsigned sG[2][2 * 3840];   // 60 KB
    const int tid = threadIdx.x;
    const int lane = tid & 63, wid = tid >> 6;         // wid 0..8
    const int l15 = lane & 15, q = lane >> 4;
    const int m = (blockIdx.x * 9 + wid) * 16 + l15;
    const float2 kk = *(const float2*)(traj + 2 * m);
    float kxh, kxl, kyh, kyl;
    ksplit(kk.x, kxh, kxl);
    ksplit(kk.y, kyh, kyl);

    f32x4 tre[12], tim[12];
    #pragma unroll
    for (int i = 0; i < 12; ++i) {
        tre[i] = (f32x4){0.f, 0.f, 0.f, 0.f};
        tim[i] = (f32x4){0.f, 0.f, 0.f, 0.f};
    }

    float bc, bs;
    { const float ph = redphase(kyh, kyl, (float)(q * 4 - 96)); 
      bc = __builtin_amdgcn_cosf(ph); bs = __builtin_amdgcn_sinf(ph); }
    const float r1c = __builtin_amdgcn_cosf(kk.y), r1s = __builtin_amdgcn_sinf(kk.y);
    float r16c, r16s;
    { float g = kk.y * 16.f; g -= rintf(g);
      r16c = __builtin_amdgcn_cosf(g); r16s = __builtin_amdgcn_sinf(g); }

    u32x4 st[3];
    fw_stage_load(Ghi, Glo, tid, 0, st);
    fw_stage_write(&sG[0][0], tid, st);
    __syncthreads();

    for (int ch = 0; ch < 12; ++ch) {
        if (ch < 11) fw_stage_load(Ghi, Glo, tid, (ch + 1) * 16, st);

        u32x4 Ph, Pl, Qh, Ql;
        {
            float c = bc, s = bs;
            #pragma unroll
            for (int r = 0; r < 4; ++r) {
                unsigned h, l; split_pk(c, s, h, l);
                Ph[r] = h; Pl[r] = l;
                Qh[r] = rot16(h) ^ 0x00008000u;
                Ql[r] = rot16(l) ^ 0x00008000u;
                const float nc = c * r1c - s * r1s, ns = s * r1c + c * r1s;
                c = nc; s = ns;
            }
            const float nbc = bc * r16c - bs * r16s, nbs = bs * r16c + bc * r16s;
            bc = nbc; bs = nbs;
        }

        const unsigned* sb = &sG[ch & 1][0];
        #pragma unroll
        for (int si = 0; si < 12; ++si) {
            const int base = (si * 16 + l15) * 20 + q * 4;
            const u32x4 gh = *(const u32x4*)(sb + base);
            const u32x4 gl = *(const u32x4*)(sb + 3840 + base);
            tre[si] = mfma_bf16(gh, Ph, tre[si]);
            tre[si] = mfma_bf16(gh, Pl, tre[si]);
            tre[si] = mfma_bf16(gl, Ph, tre[si]);
            tim[si] = mfma_bf16(gh, Qh, tim[si]);
            tim[si] = mfma_bf16(gh, Ql, tim[si]);
            tim[si] = mfma_bf16(gl, Qh, tim[si]);
        }

        if (ch < 11) {
            __syncthreads();
            fw_stage_write(&sG[(ch + 1) & 1][0], tid, st);
            __syncthreads();
        }
    }

    float qr = 0.f, qi = 0.f;
    {
        float g = kk.x * 16.f; g -= rintf(g);
        const float rc = __builtin_amdgcn_cosf(g), rs = __builtin_amdgcn_sinf(g);
        #pragma unroll
        for (int rg = 0; rg < 4; ++rg) {
            const float ph = redphase(kxh, kxl, (float)(q * 4 + rg - 96));
            float c = __builtin_amdgcn_cosf(ph), s = __builtin_amdgcn_sinf(ph);
            #pragma unroll
            for (int si = 0; si < 12; ++si) {
                const float tr = tre[si][rg], ti = tim[si][rg];
                qr += c * tr + s * ti;
                qi += c * ti - s * tr;
                const float nc = c * rc - s * rs, ns = s * rc + c * rs;
                c = nc; s = ns;
            }
        }
    }
    qr += __shfl_xor(qr, 16); qi += __shfl_xor(qi, 16);
    qr += __shfl_xor(qr, 32); qi += __shfl_xor(qi, 32);
    if (lane < 16) {
        if (mode == 0) {
            const float den = fmaxf(sqrtf(qr * qr + qi * qi), 1e-20f);
            wre[m] /= den; wim[m] /= den;
        } else {
            const float sc = sqrtf(wre[m] * wre[m] + wim[m] * wim[m]);
            qre[m] = qr * sc; qim[m] = qi * sc;
        }
    }
}

// ---------------------------------------------------------------------------
__global__ void presplit_k(const float* __restrict__ re, const float* __restrict__ im,
                           unsigned* __restrict__ Gh, unsigned* __restrict__ Gl) {
    const int e = blockIdx.x * 256 + threadIdx.x;
    unsigned h, l;
    split_pk(re[e], im[e], h, l);     // low16 = re (even K), high16 = im (odd K)
    Gh[e] = h; Gl[e] = l;
}

// Reduce PG partial images + presplit (pipe path)
__global__ void presplitP_k(const float* __restrict__ outP,
                            unsigned* __restrict__ Gh, unsigned* __restrict__ Gl) {
    const int e = blockIdx.x * 256 + threadIdx.x;
    float re = 0.f, im = 0.f;
    #pragma unroll
    for (int g = 0; g < PG; ++g) {
        re += outP[(size_t)g * (2 * MTOT) + e];
        im += outP[(size_t)g * (2 * MTOT) + MTOT + e];
    }
    unsigned h, l;
    split_pk(re, im, h, l);
    Gh[e] = h; Gl[e] = l;
}

// Reduce PG partial images -> final output
__global__ void reduceOut_k(const float* __restrict__ outP, float* __restrict__ out) {
    const int e = blockIdx.x * 256 + threadIdx.x;
    float re = 0.f, im = 0.f;
    #pragma unroll
    for (int g = 0; g < PG; ++g) {
        re += outP[(size_t)g * (2 * MTOT) + e];
        im += outP[(size_t)g * (2 * MTOT) + MTOT + e];
    }
    out[e] = re; out[MTOT + e] = im;
}

// ---------------------------------------------------------------------------
extern "C" void kernel_launch(void* const* d_in, const int* in_sizes, int n_in,
                              void* d_out, int out_size, void* d_ws, size_t ws_size,
                              hipStream_t stream)
{
    const float* xin  = (const float*)d_in[0];   // (2,192,192)
    const float* traj = (const float*)d_in[1];   // (36864,2)
    float* out = (float*)d_out;                  // (2,192,192)

    char* pb = (char*)d_ws;
    unsigned* AS = (unsigned*)pb; pb += (size_t)2304 * 6144 * 4;   // 56.6 MB
    unsigned* BS = (unsigned*)pb; pb += (size_t)2304 * 6144 * 4;   // 56.6 MB
    float* outP = (float*)pb; pb += (size_t)PG * 2 * MTOT * 4;
    float* wr   = (float*)pb; pb += MTOT * 4;
    float* wi   = (float*)pb; pb += MTOT * 4;
    float* dre  = (float*)pb; pb += MTOT * 4;
    float* dim_ = (float*)pb; pb += MTOT * 4;
    unsigned* Ghi = (unsigned*)pb; pb += MTOT * 4;
    unsigned* Glo = (unsigned*)pb; pb += MTOT * 4;

    precompP_k<<<dim3(MTOT / 256, NPIX), 256, 0, stream>>>(traj, 0, AS);
    precompP_k<<<dim3(MTOT / 256, NPIX), 256, 0, stream>>>(traj, 1, BS);
    winit_k<<<MTOT / 256, 256, 0, stream>>>(wr, wi);

    for (int it = 0; it < 3; ++it) {
        hipMemsetAsync(outP, 0, (size_t)PG * 2 * MTOT * 4, stream);
        adj_mfma_k<<<dim3(4, SPLITS), 256, 0, stream>>>(wr, wi, AS, BS, outP);
        presplitP_k<<<MTOT / 256, 256, 0, stream>>>(outP, Ghi, Glo);
        fwdq_k<<<256, 576, 0, stream>>>(traj, Ghi, Glo, wr, wi, 0, dre, dim_);
    }

    presplit_k<<<MTOT / 256, 256, 0, stream>>>(xin, xin + MTOT, Ghi, Glo);
    fwdq_k<<<256, 576, 0, stream>>>(traj, Ghi, Glo, wr, wi, 1, dre, dim_);
    hipMemsetAsync(outP, 0, (size_t)PG * 2 * MTOT * 4, stream);
    adj_mfma_k<<<dim3(4, SPLITS), 256, 0, stream>>>(dre, dim_, AS, BS, outP);
    reduceOut_k<<<MTOT / 256, 256, 0, stream>>>(outP, out);
}